// Round 3
// baseline (2049.049 us; speedup 1.0000x reference)
//
#include <hip/hip_runtime.h>

// BSScanThru: out = brev8( (brev8(a) + brev8(b) + carry-chain) mod 256 ) & ~b
// Single-pass chained scan with decoupled lookback.
//
// Inputs: int32 (values 0..255). Output: int32.
//
// Tiles of 4096 elems (256 thr x 16). Dynamic tile-id via atomic counter
// (forward progress independent of dispatch order). Per-tile (g,p) carry
// aggregate published device-scope; lookback early-exits when the combined
// suffix has p==0 (always, on random data: p = AND of 4096 propagate bits).

#define BLK 256
#define EPT 16
#define TILE (BLK * EPT)   // 4096

#define ST_AGG 1u
#define ST_PRE 2u

// (g,p) packed: bit0 = g, bit1 = p. Identity: g=0,p=1 -> 2u.
__device__ __forceinline__ unsigned gp_combine(unsigned l, unsigned r) {
    unsigned g = (r & 1u) | ((r >> 1) & l & 1u);   // gr | (pr & gl)
    unsigned p = (l >> 1) & (r >> 1) & 1u;         // pl & pr
    return g | (p << 1);
}

__device__ __forceinline__ unsigned brev8(unsigned x) {
    return __brev(x) >> 24;
}

__global__ __launch_bounds__(BLK) void bss_fused(const int* __restrict__ a,
                                                 const int* __restrict__ b,
                                                 int* __restrict__ out,
                                                 unsigned* __restrict__ flags,
                                                 unsigned* __restrict__ counter) {
    __shared__ unsigned s_tile;
    __shared__ unsigned sh[BLK];
    __shared__ unsigned s_cin;

    const int tid = threadIdx.x;
    if (tid == 0) s_tile = atomicAdd(counter, 1u);   // device-scope by default
    __syncthreads();
    const unsigned tile = s_tile;
    const int base = (int)tile * TILE + tid * EPT;

    // ---- load 16 elems/thread (4x int4 each stream) ----
    int4 av[4], bv[4];
#pragma unroll
    for (int q = 0; q < 4; ++q) {
        av[q] = *reinterpret_cast<const int4*>(a + base + q * 4);
        bv[q] = *reinterpret_cast<const int4*>(b + base + q * 4);
    }
    const int* ae = reinterpret_cast<const int*>(av);
    const int* be = reinterpret_cast<const int*>(bv);

    // ---- per-element wrapped sum + (g,p); thread-serial aggregate ----
    unsigned c[EPT], gp[EPT];
    unsigned tagg = 2u;  // identity
#pragma unroll
    for (int k = 0; k < EPT; ++k) {
        unsigned s = brev8((unsigned)ae[k] & 0xFFu) + brev8((unsigned)be[k] & 0xFFu);
        c[k] = s & 0xFFu;
        gp[k] = (s >> 8) | ((unsigned)(c[k] == 0xFFu) << 1);
        tagg = gp_combine(tagg, gp[k]);
    }

    // ---- block-wide inclusive Hillis-Steele scan of thread aggregates ----
    sh[tid] = tagg;
    __syncthreads();
    for (int off = 1; off < BLK; off <<= 1) {
        unsigned v = sh[tid];
        if (tid >= off) v = gp_combine(sh[tid - off], v);
        __syncthreads();
        sh[tid] = v;
        __syncthreads();
    }
    const unsigned ex = (tid == 0) ? 2u : sh[tid - 1];  // exclusive thread prefix

    // ---- publish aggregate, decoupled lookback (thread 0) ----
    if (tid == 0) {
        const unsigned agg = sh[BLK - 1] & 3u;
        if (tile == 0) {
            __hip_atomic_store(&flags[0], (ST_PRE << 2) | agg,
                               __ATOMIC_RELEASE, __HIP_MEMORY_SCOPE_AGENT);
            s_cin = 0u;
        } else {
            __hip_atomic_store(&flags[tile], (ST_AGG << 2) | agg,
                               __ATOMIC_RELEASE, __HIP_MEMORY_SCOPE_AGENT);
            unsigned acc = 2u;        // aggregate of tiles (i+1 .. tile-1)
            unsigned prefix;          // will hold gp of tiles (0 .. tile-1)
            int i = (int)tile - 1;
            for (;;) {
                unsigned w;
                do {
                    w = __hip_atomic_load(&flags[i], __ATOMIC_ACQUIRE,
                                          __HIP_MEMORY_SCOPE_AGENT);
                } while ((w >> 2) == 0u);
                const unsigned v = w & 3u;
                if ((w >> 2) == ST_PRE) { prefix = gp_combine(v, acc); break; }
                acc = gp_combine(v, acc);
                if ((acc >> 1) == 0u) { prefix = acc; break; }  // p==0: history irrelevant
                --i;
            }
            __hip_atomic_store(&flags[tile], (ST_PRE << 2) | gp_combine(prefix, agg),
                               __ATOMIC_RELEASE, __HIP_MEMORY_SCOPE_AGENT);
            s_cin = prefix & 1u;      // carry into this tile
        }
    }
    __syncthreads();
    const unsigned cb = s_cin;

    // ---- resolve carries, final byte op, store ----
    unsigned cin = (ex & 1u) | (((ex >> 1) & 1u) & cb);
    int4 o[4];
    int* of = reinterpret_cast<int*>(o);
#pragma unroll
    for (int k = 0; k < EPT; ++k) {
        unsigned bev = (unsigned)be[k] & 0xFFu;
        unsigned res = (c[k] + cin) & 0xFFu;
        of[k] = (int)(brev8(res) & (~bev & 0xFFu));
        cin = (gp[k] & 1u) | (((gp[k] >> 1) & 1u) & cin);
    }
#pragma unroll
    for (int q = 0; q < 4; ++q)
        *reinterpret_cast<int4*>(out + base + q * 4) = o[q];
}

extern "C" void kernel_launch(void* const* d_in, const int* in_sizes, int n_in,
                              void* d_out, int out_size, void* d_ws, size_t ws_size,
                              hipStream_t stream) {
    const int* a = (const int*)d_in[0];
    const int* b = (const int*)d_in[1];
    int* out = (int*)d_out;
    const int n = in_sizes[0];      // 67108864
    const int nb = n / TILE;        // 16384

    unsigned* flags = (unsigned*)d_ws;
    unsigned* counter = flags + nb;

    // reset flags + counter (graph-capture-safe async memset)
    hipMemsetAsync(d_ws, 0, (size_t)(nb + 16) * sizeof(unsigned), stream);

    bss_fused<<<nb, BLK, 0, stream>>>(a, b, out, flags, counter);
}

// Round 4
// 153.946 us; speedup vs baseline: 13.3101x; 13.3101x over previous
//
#include <hip/hip_runtime.h>

// BSScanThru: out = brev8( (brev8(a) + brev8(b) + carry-chain) mod 256 ) & ~b
//
// Single-pass, zero inter-block communication.
//
// Carry-lookahead identity: p_j = (c_j == 255) implies g_j = 0 (a wrapped
// byte sum cannot be exactly 255 while also wrapping). Therefore the carry
// into any position equals g of the NEAREST preceding element with c != 255.
// Each block computes its own carry-in by peeking backward from its tile
// base: one wave reads the preceding 64 elements (coalesced), ballots
// c != 255, and takes g from the highest such lane. Windows step back (prob
// ~2^-512 per extra window) until a non-propagating element or array start;
// indices < 0 behave as {c=0, g=0}, which terminates at the start with
// carry 0 and also handles block 0 with no special case.
//
// Inputs: int32 (values 0..255). Output: int32.

#define BLK 256
#define EPT 16
#define TILE (BLK * EPT)   // 4096

// (g,p) packed: bit0 = g, bit1 = p. Identity: g=0,p=1 -> 2u.
__device__ __forceinline__ unsigned gp_combine(unsigned l, unsigned r) {
    unsigned g = (r & 1u) | ((r >> 1) & l & 1u);   // gr | (pr & gl)
    unsigned p = (l >> 1) & (r >> 1) & 1u;         // pl & pr
    return g | (p << 1);
}

__device__ __forceinline__ unsigned brev8(unsigned x) {
    return __brev(x) >> 24;
}

__global__ __launch_bounds__(BLK) void bss_onepass(const int* __restrict__ a,
                                                   const int* __restrict__ b,
                                                   int* __restrict__ out) {
    __shared__ unsigned sh[BLK];
    __shared__ unsigned s_cin;

    const int tid = threadIdx.x;
    const long base0 = (long)blockIdx.x * TILE;
    const int base = (int)base0 + tid * EPT;

    // ---- load 16 elems/thread ----
    int4 av[4], bv[4];
#pragma unroll
    for (int q = 0; q < 4; ++q) {
        av[q] = *reinterpret_cast<const int4*>(a + base + q * 4);
        bv[q] = *reinterpret_cast<const int4*>(b + base + q * 4);
    }
    const int* ae = reinterpret_cast<const int*>(av);
    const int* be = reinterpret_cast<const int*>(bv);

    // ---- per-element wrapped sum + (g,p); thread-serial aggregate ----
    unsigned c[EPT], gp[EPT];
    unsigned tagg = 2u;  // identity
#pragma unroll
    for (int k = 0; k < EPT; ++k) {
        unsigned s = brev8((unsigned)ae[k] & 0xFFu) + brev8((unsigned)be[k] & 0xFFu);
        c[k] = s & 0xFFu;
        gp[k] = (s >> 8) | ((unsigned)(c[k] == 0xFFu) << 1);
        tagg = gp_combine(tagg, gp[k]);
    }

    // ---- block carry-in via backward peek (wave 0 only, overlaps scan) ----
    if (tid < 64) {
        unsigned cb = 0u;
        long w = base0 - 64;
        for (;;) {
            long idx = w + tid;
            unsigned cc = 0u, gg = 0u;   // idx < 0: virtual non-propagating, g=0
            if (idx >= 0) {
                unsigned s = brev8((unsigned)a[idx] & 0xFFu) +
                             brev8((unsigned)b[idx] & 0xFFu);
                cc = s & 0xFFu;
                gg = s >> 8;
            }
            unsigned long long m = __ballot(cc != 0xFFu);
            if (m) {
                int hi = 63 - __clzll(m);        // nearest to base
                cb = (unsigned)__shfl((int)gg, hi, 64);
                break;
            }
            w -= 64;
        }
        if (tid == 0) s_cin = cb;
    }

    // ---- block-wide inclusive Hillis-Steele scan of thread aggregates ----
    sh[tid] = tagg;
    __syncthreads();
    for (int off = 1; off < BLK; off <<= 1) {
        unsigned v = sh[tid];
        if (tid >= off) v = gp_combine(sh[tid - off], v);
        __syncthreads();
        sh[tid] = v;
        __syncthreads();
    }
    const unsigned ex = (tid == 0) ? 2u : sh[tid - 1];  // exclusive thread prefix

    const unsigned cb = s_cin;  // safe: last scan iteration's __syncthreads ordered it

    // ---- resolve carries, final byte op, store ----
    unsigned cin = (ex & 1u) | (((ex >> 1) & 1u) & cb);
    int4 o[4];
    int* of = reinterpret_cast<int*>(o);
#pragma unroll
    for (int k = 0; k < EPT; ++k) {
        unsigned bev = (unsigned)be[k] & 0xFFu;
        unsigned res = (c[k] + cin) & 0xFFu;
        of[k] = (int)(brev8(res) & (~bev & 0xFFu));
        cin = (gp[k] & 1u) | (((gp[k] >> 1) & 1u) & cin);
    }
#pragma unroll
    for (int q = 0; q < 4; ++q)
        *reinterpret_cast<int4*>(out + base + q * 4) = o[q];
}

extern "C" void kernel_launch(void* const* d_in, const int* in_sizes, int n_in,
                              void* d_out, int out_size, void* d_ws, size_t ws_size,
                              hipStream_t stream) {
    const int* a = (const int*)d_in[0];
    const int* b = (const int*)d_in[1];
    int* out = (int*)d_out;
    const int n = in_sizes[0];      // 67108864
    const int nb = n / TILE;        // 16384

    bss_onepass<<<nb, BLK, 0, stream>>>(a, b, out);
}

// Round 5
// 150.026 us; speedup vs baseline: 13.6580x; 1.0261x over previous
//
#include <hip/hip_runtime.h>

// BSScanThru: out = brev8( (brev8(a) + brev8(b) + carry-chain) mod 256 ) & ~b
//
// Single-pass, zero inter-block communication, ONE barrier per block.
//
// Carry-lookahead identity: p_j = (c_j == 255) implies g_j = 0 (a wrapped
// byte sum cannot be exactly 255 while also wrapping). Therefore the carry
// into any position equals g of the NEAREST preceding element with c != 255.
// Each block computes its own carry-in by peeking backward from its tile
// base (wave 0: 64 coalesced elems per window, ballot c != 255, take g of
// the highest lane; step back on all-propagate, prob ~2^-512). Indices < 0
// act as {c=0,g=0} -> handles block 0 / array start with no special case.
//
// Block scan: per-wave __shfl_up carry-lookahead scan (register-only),
// 4 wave aggregates combined through LDS with a single __syncthreads.
//
// Inputs: int32 (values 0..255). Output: int32.

#define BLK 256
#define EPT 16
#define TILE (BLK * EPT)   // 4096

// (g,p) packed: bit0 = g, bit1 = p. Identity: g=0,p=1 -> 2u.
__device__ __forceinline__ unsigned gp_combine(unsigned l, unsigned r) {
    unsigned g = (r & 1u) | ((r >> 1) & l & 1u);   // gr | (pr & gl)
    unsigned p = (l >> 1) & (r >> 1) & 1u;         // pl & pr
    return g | (p << 1);
}

__device__ __forceinline__ unsigned brev8(unsigned x) {
    return __brev(x) >> 24;
}

__global__ __launch_bounds__(BLK) void bss_onepass(const int* __restrict__ a,
                                                   const int* __restrict__ b,
                                                   int* __restrict__ out) {
    __shared__ unsigned sh_w[4];
    __shared__ unsigned s_cin;

    const int tid = threadIdx.x;
    const int lane = tid & 63;
    const int wid = tid >> 6;
    const long base0 = (long)blockIdx.x * TILE;
    const int base = (int)base0 + tid * EPT;

    // ---- load 16 elems/thread ----
    int4 av[4], bv[4];
#pragma unroll
    for (int q = 0; q < 4; ++q) {
        av[q] = *reinterpret_cast<const int4*>(a + base + q * 4);
        bv[q] = *reinterpret_cast<const int4*>(b + base + q * 4);
    }
    const int* ae = reinterpret_cast<const int*>(av);
    const int* be = reinterpret_cast<const int*>(bv);

    // ---- per-element wrapped sum + (g,p); thread-serial aggregate ----
    unsigned c[EPT], gp[EPT];
    unsigned tagg = 2u;  // identity
#pragma unroll
    for (int k = 0; k < EPT; ++k) {
        unsigned s = brev8((unsigned)ae[k] & 0xFFu) + brev8((unsigned)be[k] & 0xFFu);
        c[k] = s & 0xFFu;
        gp[k] = (s >> 8) | ((unsigned)(c[k] == 0xFFu) << 1);
        tagg = gp_combine(tagg, gp[k]);
    }

    // ---- block carry-in via backward peek (wave 0 only) ----
    if (wid == 0) {
        unsigned cb = 0u;
        long w = base0 - 64;
        for (;;) {
            long idx = w + lane;
            unsigned cc = 0u, gg = 0u;   // idx < 0: virtual non-propagating, g=0
            if (idx >= 0) {
                unsigned s = brev8((unsigned)a[idx] & 0xFFu) +
                             brev8((unsigned)b[idx] & 0xFFu);
                cc = s & 0xFFu;
                gg = s >> 8;
            }
            unsigned long long m = __ballot(cc != 0xFFu);
            if (m) {
                int hi = 63 - __clzll(m);        // nearest to tile base
                cb = (unsigned)__shfl((int)gg, hi, 64);
                break;
            }
            w -= 64;
        }
        if (lane == 0) s_cin = cb;
    }

    // ---- per-wave inclusive shuffle scan (register-only) ----
    unsigned v = tagg;
#pragma unroll
    for (int off = 1; off < 64; off <<= 1) {
        unsigned u = (unsigned)__shfl_up((int)v, (unsigned)off, 64);
        if (lane >= off) v = gp_combine(u, v);
    }
    if (lane == 63) sh_w[wid] = v;
    __syncthreads();   // publishes sh_w AND s_cin

    // prefix over earlier waves (≤3 combines, LDS broadcast reads)
    unsigned pre = 2u;
#pragma unroll
    for (int w = 0; w < 3; ++w)
        if (w < wid) pre = gp_combine(pre, sh_w[w]);

    // thread-exclusive prefix within block
    unsigned exw = (unsigned)__shfl_up((int)v, 1u, 64);
    const unsigned ex = (lane == 0) ? pre : gp_combine(pre, exw);

    const unsigned cb = s_cin;

    // ---- resolve carries, final byte op, store ----
    unsigned cin = (ex & 1u) | (((ex >> 1) & 1u) & cb);
    int4 o[4];
    int* of = reinterpret_cast<int*>(o);
#pragma unroll
    for (int k = 0; k < EPT; ++k) {
        unsigned bev = (unsigned)be[k] & 0xFFu;
        unsigned res = (c[k] + cin) & 0xFFu;
        of[k] = (int)(brev8(res) & (~bev & 0xFFu));
        cin = (gp[k] & 1u) | (((gp[k] >> 1) & 1u) & cin);
    }
#pragma unroll
    for (int q = 0; q < 4; ++q)
        *reinterpret_cast<int4*>(out + base + q * 4) = o[q];
}

extern "C" void kernel_launch(void* const* d_in, const int* in_sizes, int n_in,
                              void* d_out, int out_size, void* d_ws, size_t ws_size,
                              hipStream_t stream) {
    const int* a = (const int*)d_in[0];
    const int* b = (const int*)d_in[1];
    int* out = (int*)d_out;
    const int n = in_sizes[0];      // 67108864
    const int nb = n / TILE;        // 16384

    bss_onepass<<<nb, BLK, 0, stream>>>(a, b, out);
}